// Round 13
// baseline (293.931 us; speedup 1.0000x reference)
//
#include <hip/hip_runtime.h>
#include <hip/hip_bf16.h>

// ---------------------------------------------------------------------------
// EdgeClassifier: 2x GCNConv + edge MLP. All node intermediates bf16.
// CSR build via bucket sort (256 nodes/bucket): bcount -> bscan -> binscatter
//   -> build (rs, col, dinv, fused xs=bf16(x*dinv)).
// Layer 1: agg in x-space -> node1 (MFMA). Layer 2: agg64 -> (node2 FOLDED
//   into the edge MLP via fused weights W2@Wc1 computed in k_prep).
// Edge MLP: coop full-line gathers of xagg2 + XOR-swizzled slab; packed-u32
//   hid with k-permuted Wc2T; attr pre-converted to bf16 (ws-guarded).
// ---------------------------------------------------------------------------

typedef __attribute__((ext_vector_type(8))) short  bf16x8;
typedef __attribute__((ext_vector_type(16))) float f32x16;

__device__ inline short f2bf(float f)
{
    union { float f; unsigned u; } v; v.f = f;
    unsigned r = v.u + 0x7fff + ((v.u >> 16) & 1);   // RNE
    return (short)(r >> 16);
}

__device__ inline float2 bfp2f(unsigned u)
{
    union { unsigned u; float f; } a, b;
    a.u = u << 16;
    b.u = u & 0xffff0000u;
    return make_float2(a.f, b.f);
}

__device__ inline unsigned packbf2(float a, float b)
{
    return (unsigned)(unsigned short)f2bf(a) | ((unsigned)(unsigned short)f2bf(b) << 16);
}

// ---------------- bucketed CSR build (bucket = dst >> 8) ----------------
__global__ __launch_bounds__(256) void k_bcount(const int* __restrict__ ei, int* __restrict__ bcnt, int E)
{
    __shared__ int h[512];
    for (int i = threadIdx.x; i < 512; i += 256) h[i] = 0;
    __syncthreads();
    for (long e = (long)blockIdx.x * 256 + threadIdx.x; e < E; e += (long)gridDim.x * 256)
        atomicAdd(&h[ei[E + e] >> 8], 1);
    __syncthreads();
    for (int i = threadIdx.x; i < 512; i += 256)
        if (h[i]) atomicAdd(&bcnt[i], h[i]);
}

__global__ __launch_bounds__(512) void k_bscan(const int* __restrict__ bcnt, int nbk, int* __restrict__ bstart)
{
    __shared__ int s[512];
    int t = threadIdx.x;
    int v = (t < nbk) ? bcnt[t] : 0;
    s[t] = v;
    __syncthreads();
    for (int o = 1; o < 512; o <<= 1) {
        int a = (t >= o) ? s[t - o] : 0;
        __syncthreads();
        s[t] += a;
        __syncthreads();
    }
    if (t < nbk) bstart[t + 1] = s[t];
    if (t == 0) bstart[0] = 0;
}

__global__ __launch_bounds__(256) void k_binscatter(const int* __restrict__ ei, const int* __restrict__ bstart,
                                                    int* __restrict__ bcur, int2* __restrict__ ebs, int E)
{
    __shared__ int cnt[512], gb[512];
    const int tid = threadIdx.x;
    for (int i = tid; i < 512; i += 256) cnt[i] = 0;
    __syncthreads();
    const int base = blockIdx.x * 4096;
    int d[16], lp[16];
#pragma unroll
    for (int i = 0; i < 16; ++i) {
        int e = base + i * 256 + tid;
        if (e < E) {
            d[i] = ei[E + e];
            lp[i] = atomicAdd(&cnt[d[i] >> 8], 1);
        } else d[i] = -1;
    }
    __syncthreads();
    for (int i = tid; i < 512; i += 256) gb[i] = cnt[i] ? atomicAdd(&bcur[i], cnt[i]) : 0;
    __syncthreads();
#pragma unroll
    for (int i = 0; i < 16; ++i) {
        if (d[i] >= 0) {
            int e = base + i * 256 + tid;
            int b = d[i] >> 8;
            int2 p;
            p.x = ei[e];
            p.y = d[i];
            ebs[(size_t)bstart[b] + gb[b] + lp[i]] = p;
        }
    }
}

// block per bucket: rs, col, dinv + fused xs = bf16(x*dinv)
__global__ __launch_bounds__(256) void k_build(const int2* __restrict__ ebs, const int* __restrict__ bstart,
                                               int* __restrict__ rs, int* __restrict__ col,
                                               float* __restrict__ dinv,
                                               const float* __restrict__ x, unsigned short* __restrict__ xs,
                                               int N, int E)
{
    __shared__ int cnt[256], lstart[256], cnt2[256];
    const int b = blockIdx.x;
    const int base = b << 8;
    const int tid = threadIdx.x;
    cnt[tid] = 0; cnt2[tid] = 0;
    __syncthreads();
    const int s0 = bstart[b], s1 = bstart[b + 1];
    for (int i = s0 + tid; i < s1; i += 256) atomicAdd(&cnt[ebs[i].y - base], 1);
    __syncthreads();
    const int v = cnt[tid];
    lstart[tid] = v;
    __syncthreads();
    for (int o = 1; o < 256; o <<= 1) {
        int a = (tid >= o) ? lstart[tid - o] : 0;
        __syncthreads();
        lstart[tid] += a;
        __syncthreads();
    }
    const int node = base + tid;
    if (node < N) {
        rs[node] = s0 + lstart[tid] - v;
        dinv[node] = rsqrtf((float)(v + 1));
    }
    if (b == 0 && tid == 0) rs[N] = E;
    __syncthreads();
    for (int i = s0 + tid; i < s1; i += 256) {
        int2 p = ebs[i];
        int ln = p.y - base;
        int pos = atomicAdd(&cnt2[ln], 1);
        col[s0 + (lstart[ln] - cnt[ln]) + pos] = p.x;
    }
#pragma unroll
    for (int i = 0; i < 16; ++i) {
        int id = i * 256 + tid;
        int ni = id >> 4, pr = id & 15;
        int nd = base + ni;
        if (nd < N) {
            float dv = rsqrtf((float)(cnt[ni] + 1));
            float2 xv = *(const float2*)&x[(size_t)nd * 32 + pr * 2];
            *(unsigned*)(xs + (size_t)nd * 32 + pr * 2) = packbf2(xv.x * dv, xv.y * dv);
        }
    }
}

// ---------------- weight prep ----------------
// Wc1T[j][144] FUSED:  p<64:  sum_k W2[p][k]*Wc1[k][j]
//                      p<128: sum_k W2[p-64][k]*Wc1[64+k][j]
//                      else:  Wc1[p][j]
// bcp[j] = bc1[j] + sum_k b2[k]*(Wc1[k][j]+Wc1[64+k][j])
// Wc2T[32][64] k-permuted (p>>1 + 32*(p&1)); W1T[64][32].
__global__ __launch_bounds__(256) void k_prep(const float* __restrict__ Wc1, const float* __restrict__ Wc2,
                                              const float* __restrict__ W2, const float* __restrict__ W1,
                                              const float* __restrict__ bc1, const float* __restrict__ b2,
                                              short* __restrict__ Wc1T, short* __restrict__ Wc2T,
                                              short* __restrict__ W1T, float* __restrict__ bcp)
{
    int t = blockIdx.x * 256 + threadIdx.x;
    if (t < 9216) {
        int j = t / 144, p = t - j * 144;
        float val;
        if (p < 64) {
            float s = 0.f;
            for (int k = 0; k < 64; ++k) s = fmaf(W2[p * 64 + k], Wc1[k * 64 + j], s);
            val = s;
        } else if (p < 128) {
            int m = p - 64;
            float s = 0.f;
            for (int k = 0; k < 64; ++k) s = fmaf(W2[m * 64 + k], Wc1[(64 + k) * 64 + j], s);
            val = s;
        } else {
            val = Wc1[p * 64 + j];
        }
        Wc1T[t] = f2bf(val);
    } else if (t < 11264) {
        int u = t - 9216;
        int rr = u / 64, p = u - rr * 64;
        int k = (p >> 1) + ((p & 1) << 5);
        Wc2T[u] = (rr < 5) ? f2bf(Wc2[k * 5 + rr]) : (short)0;
    } else if (t < 13312) {
        int u = t - 11264;
        int j = u / 32, k = u - j * 32;
        W1T[u] = f2bf(W1[k * 64 + j]);
    } else if (t < 13376) {
        int j = t - 13312;
        float s = bc1[j];
        for (int k = 0; k < 64; ++k) s = fmaf(b2[k], Wc1[k * 64 + j] + Wc1[(64 + k) * 64 + j], s);
        bcp[j] = s;
    }
}

// ---------------- eattr -> bf16 ----------------
__global__ __launch_bounds__(256) void k_ea(const float* __restrict__ ea, unsigned short* __restrict__ eabf, long n4)
{
    long id = (long)blockIdx.x * 256 + threadIdx.x;
    if (id >= n4) return;
    float4 v = *(const float4*)&ea[id * 4];
    short4 o;
    o.x = f2bf(v.x); o.y = f2bf(v.y); o.z = f2bf(v.z); o.w = f2bf(v.w);
    *(short4*)&eabf[id * 4] = o;
}

// ---------------- x-space aggregation: 8 lanes/node, uint2 = full 64B row ----------------
__global__ __launch_bounds__(256) void k_agg_x(const unsigned short* __restrict__ xs,
                                               const float* __restrict__ dinv,
                                               const int* __restrict__ rs, const int* __restrict__ col,
                                               unsigned short* __restrict__ xagg, int n)
{
    const int tid = threadIdx.x;
    const int l   = tid & 7;
    const int v   = blockIdx.x * 32 + (tid >> 3);
    if (v >= n) return;

    uint2 sv = *(const uint2*)(xs + (size_t)v * 32 + l * 4);
    float2 aL = bfp2f(sv.x), aH = bfp2f(sv.y);
    int i = rs[v];
    const int end = rs[v + 1];
    for (; i + 8 <= end; i += 8) {
        int c0 = col[i],     c1 = col[i + 1], c2 = col[i + 2], c3 = col[i + 3];
        int c4 = col[i + 4], c5 = col[i + 5], c6 = col[i + 6], c7 = col[i + 7];
        uint2 u0 = *(const uint2*)(xs + (size_t)c0 * 32 + l * 4);
        uint2 u1 = *(const uint2*)(xs + (size_t)c1 * 32 + l * 4);
        uint2 u2 = *(const uint2*)(xs + (size_t)c2 * 32 + l * 4);
        uint2 u3 = *(const uint2*)(xs + (size_t)c3 * 32 + l * 4);
        uint2 u4 = *(const uint2*)(xs + (size_t)c4 * 32 + l * 4);
        uint2 u5 = *(const uint2*)(xs + (size_t)c5 * 32 + l * 4);
        uint2 u6 = *(const uint2*)(xs + (size_t)c6 * 32 + l * 4);
        uint2 u7 = *(const uint2*)(xs + (size_t)c7 * 32 + l * 4);
        float2 p;
        p = bfp2f(u0.x); aL.x += p.x; aL.y += p.y; p = bfp2f(u0.y); aH.x += p.x; aH.y += p.y;
        p = bfp2f(u1.x); aL.x += p.x; aL.y += p.y; p = bfp2f(u1.y); aH.x += p.x; aH.y += p.y;
        p = bfp2f(u2.x); aL.x += p.x; aL.y += p.y; p = bfp2f(u2.y); aH.x += p.x; aH.y += p.y;
        p = bfp2f(u3.x); aL.x += p.x; aL.y += p.y; p = bfp2f(u3.y); aH.x += p.x; aH.y += p.y;
        p = bfp2f(u4.x); aL.x += p.x; aL.y += p.y; p = bfp2f(u4.y); aH.x += p.x; aH.y += p.y;
        p = bfp2f(u5.x); aL.x += p.x; aL.y += p.y; p = bfp2f(u5.y); aH.x += p.x; aH.y += p.y;
        p = bfp2f(u6.x); aL.x += p.x; aL.y += p.y; p = bfp2f(u6.y); aH.x += p.x; aH.y += p.y;
        p = bfp2f(u7.x); aL.x += p.x; aL.y += p.y; p = bfp2f(u7.y); aH.x += p.x; aH.y += p.y;
    }
    for (; i < end; ++i) {
        uint2 u = *(const uint2*)(xs + (size_t)col[i] * 32 + l * 4);
        float2 p;
        p = bfp2f(u.x); aL.x += p.x; aL.y += p.y;
        p = bfp2f(u.y); aH.x += p.x; aH.y += p.y;
    }
    const float dv = dinv[v];
    uint2 o;
    o.x = packbf2(dv * aL.x, dv * aL.y);
    o.y = packbf2(dv * aH.x, dv * aH.y);
    *(uint2*)(xagg + (size_t)v * 32 + l * 4) = o;
}

// ---------------- 64-dim aggregation: 16 lanes/node, uint2 = full 128B row ----------------
__global__ __launch_bounds__(256) void k_agg64(const unsigned short* __restrict__ hsc,
                                               const float* __restrict__ dinv,
                                               const int* __restrict__ rs, const int* __restrict__ col,
                                               unsigned short* __restrict__ out, int n)
{
    const int tid = threadIdx.x;
    const int l   = tid & 15;
    const int v   = blockIdx.x * 16 + (tid >> 4);
    if (v >= n) return;

    uint2 sv = *(const uint2*)(hsc + (size_t)v * 64 + l * 4);
    float2 aL = bfp2f(sv.x), aH = bfp2f(sv.y);
    int i = rs[v];
    const int end = rs[v + 1];
    for (; i + 8 <= end; i += 8) {
        int c0 = col[i],     c1 = col[i + 1], c2 = col[i + 2], c3 = col[i + 3];
        int c4 = col[i + 4], c5 = col[i + 5], c6 = col[i + 6], c7 = col[i + 7];
        uint2 u0 = *(const uint2*)(hsc + (size_t)c0 * 64 + l * 4);
        uint2 u1 = *(const uint2*)(hsc + (size_t)c1 * 64 + l * 4);
        uint2 u2 = *(const uint2*)(hsc + (size_t)c2 * 64 + l * 4);
        uint2 u3 = *(const uint2*)(hsc + (size_t)c3 * 64 + l * 4);
        uint2 u4 = *(const uint2*)(hsc + (size_t)c4 * 64 + l * 4);
        uint2 u5 = *(const uint2*)(hsc + (size_t)c5 * 64 + l * 4);
        uint2 u6 = *(const uint2*)(hsc + (size_t)c6 * 64 + l * 4);
        uint2 u7 = *(const uint2*)(hsc + (size_t)c7 * 64 + l * 4);
        float2 p;
        p = bfp2f(u0.x); aL.x += p.x; aL.y += p.y; p = bfp2f(u0.y); aH.x += p.x; aH.y += p.y;
        p = bfp2f(u1.x); aL.x += p.x; aL.y += p.y; p = bfp2f(u1.y); aH.x += p.x; aH.y += p.y;
        p = bfp2f(u2.x); aL.x += p.x; aL.y += p.y; p = bfp2f(u2.y); aH.x += p.x; aH.y += p.y;
        p = bfp2f(u3.x); aL.x += p.x; aL.y += p.y; p = bfp2f(u3.y); aH.x += p.x; aH.y += p.y;
        p = bfp2f(u4.x); aL.x += p.x; aL.y += p.y; p = bfp2f(u4.y); aH.x += p.x; aH.y += p.y;
        p = bfp2f(u5.x); aL.x += p.x; aL.y += p.y; p = bfp2f(u5.y); aH.x += p.x; aH.y += p.y;
        p = bfp2f(u6.x); aL.x += p.x; aL.y += p.y; p = bfp2f(u6.y); aH.x += p.x; aH.y += p.y;
        p = bfp2f(u7.x); aL.x += p.x; aL.y += p.y; p = bfp2f(u7.y); aH.x += p.x; aH.y += p.y;
    }
    for (; i < end; ++i) {
        uint2 u = *(const uint2*)(hsc + (size_t)col[i] * 64 + l * 4);
        float2 p;
        p = bfp2f(u.x); aL.x += p.x; aL.y += p.y;
        p = bfp2f(u.y); aH.x += p.x; aH.y += p.y;
    }
    const float dv = dinv[v];
    uint2 o;
    o.x = packbf2(dv * aL.x, dv * aL.y);
    o.y = packbf2(dv * aH.x, dv * aH.y);
    *(uint2*)(out + (size_t)v * 64 + l * 4) = o;
}

// ---------------- node1: h1s = relu(xagg @ W1 + b1) * dinv ----------------
__global__ __launch_bounds__(256) void k_node1(const unsigned short* __restrict__ xagg,
                                               const short* __restrict__ W1T,
                                               const float* __restrict__ b1, const float* __restrict__ dinv,
                                               unsigned short* __restrict__ h1s, int n)
{
    const int tid = threadIdx.x;
    const int w = tid >> 6, lane = tid & 63, r = lane & 31, kg = lane >> 5;
    const int nb = blockIdx.x * 128 + w * 32;

    bf16x8 a0[2], a1[2];
#pragma unroll
    for (int t = 0; t < 2; ++t) {
        a0[t] = *(const bf16x8*)&W1T[r * 32 + t * 16 + kg * 8];
        a1[t] = *(const bf16x8*)&W1T[(r + 32) * 32 + t * 16 + kg * 8];
    }

    int row = nb + r;
    if (row >= n) row = n - 1;
    f32x16 acc0 = {0.f}, acc1 = {0.f};
#pragma unroll
    for (int t = 0; t < 2; ++t) {
        bf16x8 b = *(const bf16x8*)&xagg[(size_t)row * 32 + t * 16 + kg * 8];
        acc0 = __builtin_amdgcn_mfma_f32_32x32x16_bf16(a0[t], b, acc0, 0, 0, 0);
        acc1 = __builtin_amdgcn_mfma_f32_32x32x16_bf16(a1[t], b, acc1, 0, 0, 0);
    }

    const int node = nb + r;
    if (node < n) {
        const float dv = dinv[node];
#pragma unroll
        for (int q = 0; q < 4; ++q) {
            const int j0 = 8 * q + 4 * kg;
            float4 bA = *(const float4*)&b1[j0];
            float4 bB = *(const float4*)&b1[j0 + 32];
            short4 s0, s1;
            float t0, t1;
            t0 = acc0[4 * q]     + bA.x; t0 = t0 > 0.f ? t0 : 0.f; s0.x = f2bf(t0 * dv);
            t0 = acc0[4 * q + 1] + bA.y; t0 = t0 > 0.f ? t0 : 0.f; s0.y = f2bf(t0 * dv);
            t0 = acc0[4 * q + 2] + bA.z; t0 = t0 > 0.f ? t0 : 0.f; s0.z = f2bf(t0 * dv);
            t0 = acc0[4 * q + 3] + bA.w; t0 = t0 > 0.f ? t0 : 0.f; s0.w = f2bf(t0 * dv);
            t1 = acc1[4 * q]     + bB.x; t1 = t1 > 0.f ? t1 : 0.f; s1.x = f2bf(t1 * dv);
            t1 = acc1[4 * q + 1] + bB.y; t1 = t1 > 0.f ? t1 : 0.f; s1.y = f2bf(t1 * dv);
            t1 = acc1[4 * q + 2] + bB.z; t1 = t1 > 0.f ? t1 : 0.f; s1.z = f2bf(t1 * dv);
            t1 = acc1[4 * q + 3] + bB.w; t1 = t1 > 0.f ? t1 : 0.f; s1.w = f2bf(t1 * dv);
            *(short4*)&h1s[(size_t)node * 64 + j0]      = s0;
            *(short4*)&h1s[(size_t)node * 64 + j0 + 32] = s1;
        }
    }
}

// ---------------- MFMA edge MLP (node2 folded in; gathers xagg2) ----------------
template <int ABF>
__global__ __launch_bounds__(256) void k_edge_mlp_mfma(
    const unsigned short* __restrict__ zrow, const void* __restrict__ eattr,
    const int* __restrict__ ei,
    const short* __restrict__ Wc1T, const float* __restrict__ bcp,
    const short* __restrict__ Wc2T, const float* __restrict__ bc2,
    float* __restrict__ out, int E)
{
    __shared__ char slab[4 * 8192];   // 32 KB

    const int tid = threadIdx.x;
    const int w = tid >> 6, lane = tid & 63, r = lane & 31, kg = lane >> 5;
    const int q = lane & 3, sr = lane >> 2;

    char* myslab = slab + w * 8192;

    const long eb = (long)blockIdx.x * 128 + w * 32;
    long ecl = eb + r; if (ecl >= E) ecl = E - 1;
    const int ns = ei[ecl];
    const int nd = ei[E + ecl];

    bf16x8 aa;
    if (ABF) {
        aa = *(const bf16x8*)((const unsigned short*)eattr + (size_t)ecl * 16 + kg * 8);
    } else {
        const float* arow = (const float*)eattr + (size_t)ecl * 16;
        float4 alo = *(const float4*)&arow[kg * 8];
        float4 ahi = *(const float4*)&arow[kg * 8 + 4];
        aa[0] = f2bf(alo.x); aa[1] = f2bf(alo.y); aa[2] = f2bf(alo.z); aa[3] = f2bf(alo.w);
        aa[4] = f2bf(ahi.x); aa[5] = f2bf(ahi.y); aa[6] = f2bf(ahi.z); aa[7] = f2bf(ahi.w);
    }

    // coop gathers: 4-lane groups fetch contiguous 64B per row
    {
        int n0 = __shfl(ns, sr);
        int n1 = __shfl(ns, 16 + sr);
        int m0 = __shfl(nd, sr);
        int m1 = __shfl(nd, 16 + sr);
        int4 s0 = *(const int4*)&zrow[(size_t)n0 * 64 + q * 8];
        int4 s1 = *(const int4*)&zrow[(size_t)n0 * 64 + 32 + q * 8];
        int4 s2 = *(const int4*)&zrow[(size_t)n1 * 64 + q * 8];
        int4 s3 = *(const int4*)&zrow[(size_t)n1 * 64 + 32 + q * 8];
        int4 d0 = *(const int4*)&zrow[(size_t)m0 * 64 + q * 8];
        int4 d1 = *(const int4*)&zrow[(size_t)m0 * 64 + 32 + q * 8];
        int4 d2 = *(const int4*)&zrow[(size_t)m1 * 64 + q * 8];
        int4 d3 = *(const int4*)&zrow[(size_t)m1 * 64 + 32 + q * 8];
        const int x0 = (sr ^ q) * 16, x1 = (16 + (sr ^ q)) * 16;
        *(int4*)(myslab + q * 512 + x0)              = s0;
        *(int4*)(myslab + (4 + q) * 512 + x0)        = s1;
        *(int4*)(myslab + q * 512 + x1)              = s2;
        *(int4*)(myslab + (4 + q) * 512 + x1)        = s3;
        *(int4*)(myslab + 4096 + q * 512 + x0)       = d0;
        *(int4*)(myslab + 4096 + (4 + q) * 512 + x0) = d1;
        *(int4*)(myslab + 4096 + q * 512 + x1)       = d2;
        *(int4*)(myslab + 4096 + (4 + q) * 512 + x1) = d3;
    }

    f32x16 acc0, acc1;
    const float bias0 = bcp[r], bias1 = bcp[r + 32];
#pragma unroll
    for (int i = 0; i < 16; ++i) { acc0[i] = bias0; acc1[i] = bias1; }

#pragma unroll
    for (int t = 0; t < 4; ++t) {
        const int c = 2 * t + kg;
        bf16x8 a  = *(const bf16x8*)(myslab + c * 512 + ((r ^ (c & 3)) * 16));
        bf16x8 w0 = *(const bf16x8*)&Wc1T[r * 144 + t * 16 + kg * 8];
        bf16x8 w1 = *(const bf16x8*)&Wc1T[(r + 32) * 144 + t * 16 + kg * 8];
        acc0 = __builtin_amdgcn_mfma_f32_32x32x16_bf16(a, w0, acc0, 0, 0, 0);
        acc1 = __builtin_amdgcn_mfma_f32_32x32x16_bf16(a, w1, acc1, 0, 0, 0);
    }
#pragma unroll
    for (int t = 0; t < 4; ++t) {
        const int c = 2 * t + kg;
        bf16x8 a  = *(const bf16x8*)(myslab + 4096 + c * 512 + ((r ^ (c & 3)) * 16));
        bf16x8 w0 = *(const bf16x8*)&Wc1T[r * 144 + (4 + t) * 16 + kg * 8];
        bf16x8 w1 = *(const bf16x8*)&Wc1T[(r + 32) * 144 + (4 + t) * 16 + kg * 8];
        acc0 = __builtin_amdgcn_mfma_f32_32x32x16_bf16(a, w0, acc0, 0, 0, 0);
        acc1 = __builtin_amdgcn_mfma_f32_32x32x16_bf16(a, w1, acc1, 0, 0, 0);
    }
    {
        bf16x8 w0 = *(const bf16x8*)&Wc1T[r * 144 + 128 + kg * 8];
        bf16x8 w1 = *(const bf16x8*)&Wc1T[(r + 32) * 144 + 128 + kg * 8];
        acc0 = __builtin_amdgcn_mfma_f32_32x32x16_bf16(aa, w0, acc0, 0, 0, 0);
        acc1 = __builtin_amdgcn_mfma_f32_32x32x16_bf16(aa, w1, acc1, 0, 0, 0);
    }

    // epilogue 1: relu -> packed u32 (col r, col r+32) -> swizzled hid (src half)
#pragma unroll
    for (int reg = 0; reg < 16; ++reg) {
        const int row = (reg & 3) + 8 * (reg >> 2) + 4 * kg;
        float v0 = acc0[reg]; v0 = v0 > 0.f ? v0 : 0.f;
        float v1 = acc1[reg]; v1 = v1 > 0.f ? v1 : 0.f;
        *(unsigned*)(myslab + row * 128 + ((4 * r) ^ ((row & 7) << 4))) = packbf2(v0, v1);
    }

    // layer 2 (k-space permuted to match Wc2T)
    const float bias2 = (r < 5) ? bc2[r] : 0.f;
    f32x16 acc2;
#pragma unroll
    for (int i = 0; i < 16; ++i) acc2[i] = bias2;
#pragma unroll
    for (int t2 = 0; t2 < 4; ++t2) {
        const int m = t2 * 2 + kg;
        bf16x8 a  = *(const bf16x8*)(myslab + r * 128 + ((16 * m) ^ ((r & 7) << 4)));
        bf16x8 bw = *(const bf16x8*)&Wc2T[r * 64 + t2 * 16 + kg * 8];
        acc2 = __builtin_amdgcn_mfma_f32_32x32x16_bf16(a, bw, acc2, 0, 0, 0);
    }

    // stores (edge order: contiguous 640B per wave)
#pragma unroll
    for (int reg = 0; reg < 16; ++reg) {
        const int row = (reg & 3) + 8 * (reg >> 2) + 4 * kg;
        const long eo = eb + row;
        if (r < 5 && eo < E) out[(size_t)eo * 5 + r] = acc2[reg];
    }
}

extern "C" void kernel_launch(void* const* d_in, const int* in_sizes, int n_in,
                              void* d_out, int out_size, void* d_ws, size_t ws_size,
                              hipStream_t stream)
{
    const float* x     = (const float*)d_in[0];
    const int*   ei    = (const int*)d_in[1];
    const float* eattr = (const float*)d_in[2];
    const float* W1    = (const float*)d_in[3];
    const float* b1    = (const float*)d_in[4];
    const float* W2    = (const float*)d_in[5];
    const float* b2    = (const float*)d_in[6];
    const float* Wc1   = (const float*)d_in[7];
    const float* bc1   = (const float*)d_in[8];
    const float* Wc2   = (const float*)d_in[9];
    const float* bc2   = (const float*)d_in[10];
    float* outp = (float*)d_out;

    const int N = in_sizes[0] / 32;
    const int E = in_sizes[1] / 2;
    const int nbk = (N + 255) >> 8;

    // ---- carve workspace ----
    size_t off = 0;
    char* base = (char*)d_ws;
    auto carve = [&](size_t bytes) -> void* {
        void* p = base + off;
        off += (bytes + 255) & ~(size_t)255;
        return p;
    };
    int*   bcnt   = (int*)carve(1024 * 4);           // bcnt + bcur adjacent
    int*   bcur   = bcnt + 512;
    int*   bstart = (int*)carve(520 * 4);
    float* dinv   = (float*)carve((size_t)N * 4);
    int*   rs     = (int*)carve((size_t)(N + 1) * 4);
    int*   col    = (int*)carve((size_t)E * 4);
    int2*  ebs    = (int2*)carve((size_t)E * 8);
    unsigned short* xs    = (unsigned short*)carve((size_t)N * 32 * 2);
    unsigned short* xagg  = (unsigned short*)carve((size_t)N * 32 * 2);
    unsigned short* h1s   = (unsigned short*)carve((size_t)N * 64 * 2);
    unsigned short* xagg2 = (unsigned short*)carve((size_t)N * 64 * 2);
    short* Wc1T   = (short*)carve(9216 * 2);
    short* Wc2T   = (short*)carve(2048 * 2);
    short* W1T    = (short*)carve(2048 * 2);
    float* bcp    = (float*)carve(64 * 4);
    unsigned short* eabf = (unsigned short*)carve((size_t)E * 16 * 2);   // optional
    const bool use_abf = (off <= ws_size);
    (void)n_in; (void)out_size;

    const int NAX = (N + 31) / 32;       // agg_x: 32 nodes/block
    const int NA  = (N + 15) / 16;       // agg64: 16 nodes/block
    const int NM  = (N + 127) / 128;     // node1: 128 nodes/block
    const int NT  = (E + 127) / 128;     // edge-MLP: 128 edges/block
    const int NSC = (E + 4095) / 4096;   // binscatter chunks

    hipMemsetAsync(bcnt, 0, 1024 * 4, stream);

    k_prep<<<68, 256, 0, stream>>>(Wc1, Wc2, W2, W1, bc1, b2, Wc1T, Wc2T, W1T, bcp);
    if (use_abf) k_ea<<<(int)(((long)E * 4 + 255) / 256), 256, 0, stream>>>(eattr, eabf, (long)E * 4);

    // ---- bucketed CSR build (+ fused xs) ----
    k_bcount<<<1024, 256, 0, stream>>>(ei, bcnt, E);
    k_bscan<<<1, 512, 0, stream>>>(bcnt, nbk, bstart);
    k_binscatter<<<NSC, 256, 0, stream>>>(ei, bstart, bcur, ebs, E);
    k_build<<<nbk, 256, 0, stream>>>(ebs, bstart, rs, col, dinv, x, xs, N, E);

    // ---- GCN layers (node2 folded into MLP) ----
    k_agg_x<<<NAX, 256, 0, stream>>>(xs, dinv, rs, col, xagg, N);
    k_node1<<<NM, 256, 0, stream>>>(xagg, W1T, b1, dinv, h1s, N);
    k_agg64<<<NA, 256, 0, stream>>>(h1s, dinv, rs, col, xagg2, N);

    // ---- edge MLP ----
    if (use_abf)
        k_edge_mlp_mfma<1><<<NT, 256, 0, stream>>>(xagg2, eabf, ei, Wc1T, bcp, Wc2T, bc2, outp, E);
    else
        k_edge_mlp_mfma<0><<<NT, 256, 0, stream>>>(xagg2, eattr, ei, Wc1T, bcp, Wc2T, bc2, outp, E);
}

// Round 14
// 284.494 us; speedup vs baseline: 1.0332x; 1.0332x over previous
//
#include <hip/hip_runtime.h>
#include <hip/hip_bf16.h>

// ---------------------------------------------------------------------------
// EdgeClassifier: 2x GCNConv + edge MLP. All node intermediates bf16.
// Fused pipeline (8 dispatches):
//   memset -> [prep+hist+ea] -> bscan -> binscatter -> build(+xs)
//   -> aggnode1 (agg_x + node1 MFMA fused via LDS) -> agg64 -> edge MLP.
// node2 folded into MLP weights (W2@Wc1 in prep). Edge MLP: coop full-line
// gathers + XOR-swizzled slab, packed-u32 hid, k-permuted Wc2T, bf16 attr.
// ---------------------------------------------------------------------------

typedef __attribute__((ext_vector_type(8))) short  bf16x8;
typedef __attribute__((ext_vector_type(16))) float f32x16;

__device__ inline short f2bf(float f)
{
    union { float f; unsigned u; } v; v.f = f;
    unsigned r = v.u + 0x7fff + ((v.u >> 16) & 1);   // RNE
    return (short)(r >> 16);
}

__device__ inline float2 bfp2f(unsigned u)
{
    union { unsigned u; float f; } a, b;
    a.u = u << 16;
    b.u = u & 0xffff0000u;
    return make_float2(a.f, b.f);
}

__device__ inline unsigned packbf2(float a, float b)
{
    return (unsigned)(unsigned short)f2bf(a) | ((unsigned)(unsigned short)f2bf(b) << 16);
}

// ---------------- fused: weight prep + dst histogram + eattr->bf16 ----------------
// blocks [0,68): prep; blocks [68, 68+1024): hist + ea grid-stride.
__global__ __launch_bounds__(256) void k_prep_hist_ea(
    const float* __restrict__ Wc1, const float* __restrict__ Wc2,
    const float* __restrict__ W2, const float* __restrict__ W1,
    const float* __restrict__ bc1, const float* __restrict__ b2,
    short* __restrict__ Wc1T, short* __restrict__ Wc2T,
    short* __restrict__ W1T, float* __restrict__ bcp,
    const int* __restrict__ ei, int* __restrict__ bcnt,
    const float* __restrict__ ea, unsigned short* __restrict__ eabf,
    int E, int do_ea)
{
    if (blockIdx.x < 68) {
        int t = blockIdx.x * 256 + threadIdx.x;
        if (t < 9216) {
            int j = t / 144, p = t - j * 144;
            float val;
            if (p < 64) {
                float s = 0.f;
                for (int k = 0; k < 64; ++k) s = fmaf(W2[p * 64 + k], Wc1[k * 64 + j], s);
                val = s;
            } else if (p < 128) {
                int m = p - 64;
                float s = 0.f;
                for (int k = 0; k < 64; ++k) s = fmaf(W2[m * 64 + k], Wc1[(64 + k) * 64 + j], s);
                val = s;
            } else {
                val = Wc1[p * 64 + j];
            }
            Wc1T[t] = f2bf(val);
        } else if (t < 11264) {
            int u = t - 9216;
            int rr = u / 64, p = u - rr * 64;
            int k = (p >> 1) + ((p & 1) << 5);
            Wc2T[u] = (rr < 5) ? f2bf(Wc2[k * 5 + rr]) : (short)0;
        } else if (t < 13312) {
            int u = t - 11264;
            int j = u / 32, k = u - j * 32;
            W1T[u] = f2bf(W1[k * 64 + j]);
        } else if (t < 13376) {
            int j = t - 13312;
            float s = bc1[j];
            for (int k = 0; k < 64; ++k) s = fmaf(b2[k], Wc1[k * 64 + j] + Wc1[(64 + k) * 64 + j], s);
            bcp[j] = s;
        }
        return;
    }
    const int bid = blockIdx.x - 68;
    __shared__ int h[512];
    for (int i = threadIdx.x; i < 512; i += 256) h[i] = 0;
    __syncthreads();
    for (long e = (long)bid * 256 + threadIdx.x; e < E; e += (long)1024 * 256)
        atomicAdd(&h[ei[E + e] >> 8], 1);
    __syncthreads();
    for (int i = threadIdx.x; i < 512; i += 256)
        if (h[i]) atomicAdd(&bcnt[i], h[i]);
    if (do_ea) {
        const long n4 = (long)E * 4;
        for (long id = (long)bid * 256 + threadIdx.x; id < n4; id += (long)1024 * 256) {
            float4 v = *(const float4*)&ea[id * 4];
            short4 o;
            o.x = f2bf(v.x); o.y = f2bf(v.y); o.z = f2bf(v.z); o.w = f2bf(v.w);
            *(short4*)&eabf[id * 4] = o;
        }
    }
}

__global__ __launch_bounds__(512) void k_bscan(const int* __restrict__ bcnt, int nbk, int* __restrict__ bstart)
{
    __shared__ int s[512];
    int t = threadIdx.x;
    int v = (t < nbk) ? bcnt[t] : 0;
    s[t] = v;
    __syncthreads();
    for (int o = 1; o < 512; o <<= 1) {
        int a = (t >= o) ? s[t - o] : 0;
        __syncthreads();
        s[t] += a;
        __syncthreads();
    }
    if (t < nbk) bstart[t + 1] = s[t];
    if (t == 0) bstart[0] = 0;
}

__global__ __launch_bounds__(256) void k_binscatter(const int* __restrict__ ei, const int* __restrict__ bstart,
                                                    int* __restrict__ bcur, int2* __restrict__ ebs, int E)
{
    __shared__ int cnt[512], gb[512];
    const int tid = threadIdx.x;
    for (int i = tid; i < 512; i += 256) cnt[i] = 0;
    __syncthreads();
    const int base = blockIdx.x * 4096;
    int d[16], lp[16];
#pragma unroll
    for (int i = 0; i < 16; ++i) {
        int e = base + i * 256 + tid;
        if (e < E) {
            d[i] = ei[E + e];
            lp[i] = atomicAdd(&cnt[d[i] >> 8], 1);
        } else d[i] = -1;
    }
    __syncthreads();
    for (int i = tid; i < 512; i += 256) gb[i] = cnt[i] ? atomicAdd(&bcur[i], cnt[i]) : 0;
    __syncthreads();
#pragma unroll
    for (int i = 0; i < 16; ++i) {
        if (d[i] >= 0) {
            int e = base + i * 256 + tid;
            int b = d[i] >> 8;
            int2 p;
            p.x = ei[e];
            p.y = d[i];
            ebs[(size_t)bstart[b] + gb[b] + lp[i]] = p;
        }
    }
}

// block per bucket: rs, col, dinv + fused xs = bf16(x*dinv)
__global__ __launch_bounds__(256) void k_build(const int2* __restrict__ ebs, const int* __restrict__ bstart,
                                               int* __restrict__ rs, int* __restrict__ col,
                                               float* __restrict__ dinv,
                                               const float* __restrict__ x, unsigned short* __restrict__ xs,
                                               int N, int E)
{
    __shared__ int cnt[256], lstart[256], cnt2[256];
    const int b = blockIdx.x;
    const int base = b << 8;
    const int tid = threadIdx.x;
    cnt[tid] = 0; cnt2[tid] = 0;
    __syncthreads();
    const int s0 = bstart[b], s1 = bstart[b + 1];
    for (int i = s0 + tid; i < s1; i += 256) atomicAdd(&cnt[ebs[i].y - base], 1);
    __syncthreads();
    const int v = cnt[tid];
    lstart[tid] = v;
    __syncthreads();
    for (int o = 1; o < 256; o <<= 1) {
        int a = (tid >= o) ? lstart[tid - o] : 0;
        __syncthreads();
        lstart[tid] += a;
        __syncthreads();
    }
    const int node = base + tid;
    if (node < N) {
        rs[node] = s0 + lstart[tid] - v;
        dinv[node] = rsqrtf((float)(v + 1));
    }
    if (b == 0 && tid == 0) rs[N] = E;
    __syncthreads();
    for (int i = s0 + tid; i < s1; i += 256) {
        int2 p = ebs[i];
        int ln = p.y - base;
        int pos = atomicAdd(&cnt2[ln], 1);
        col[s0 + (lstart[ln] - cnt[ln]) + pos] = p.x;
    }
#pragma unroll
    for (int i = 0; i < 16; ++i) {
        int id = i * 256 + tid;
        int ni = id >> 4, pr = id & 15;
        int nd = base + ni;
        if (nd < N) {
            float dv = rsqrtf((float)(cnt[ni] + 1));
            float2 xv = *(const float2*)&x[(size_t)nd * 32 + pr * 2];
            *(unsigned*)(xs + (size_t)nd * 32 + pr * 2) = packbf2(xv.x * dv, xv.y * dv);
        }
    }
}

// ---------------- fused agg_x + node1: block = 128 nodes ----------------
// phase 1: 2 lanes/node, each handles a 32B half of the 64B xs row; result
//   xagg (bf16, dinv-scaled) -> LDS [128][64B]. phase 2: 4 waves MFMA from
//   LDS, epilogue h1s = relu(acc+b1)*dinv (packed short4 stores).
__global__ __launch_bounds__(256) void k_aggnode1(
    const unsigned short* __restrict__ xs, const float* __restrict__ dinv,
    const int* __restrict__ rs, const int* __restrict__ col,
    const short* __restrict__ W1T, const float* __restrict__ b1,
    unsigned short* __restrict__ h1s, int n)
{
    __shared__ char xlds[128 * 64];

    const int tid  = threadIdx.x;
    const int nloc = tid >> 1;
    const int half = tid & 1;
    const int v    = blockIdx.x * 128 + nloc;

    // ---- phase 1: aggregate ----
    {
        float2 A[8];
        if (v < n) {
            const unsigned short* row = xs + (size_t)v * 32 + half * 16;
            uint4 u0 = *(const uint4*)row;
            uint4 u1 = *(const uint4*)(row + 8);
            A[0] = bfp2f(u0.x); A[1] = bfp2f(u0.y); A[2] = bfp2f(u0.z); A[3] = bfp2f(u0.w);
            A[4] = bfp2f(u1.x); A[5] = bfp2f(u1.y); A[6] = bfp2f(u1.z); A[7] = bfp2f(u1.w);
            int i = rs[v];
            const int end = rs[v + 1];
            for (; i + 4 <= end; i += 4) {
                int c0 = col[i], c1 = col[i + 1], c2 = col[i + 2], c3 = col[i + 3];
                uint4 g0 = *(const uint4*)(xs + (size_t)c0 * 32 + half * 16);
                uint4 g1 = *(const uint4*)(xs + (size_t)c0 * 32 + half * 16 + 8);
                uint4 g2 = *(const uint4*)(xs + (size_t)c1 * 32 + half * 16);
                uint4 g3 = *(const uint4*)(xs + (size_t)c1 * 32 + half * 16 + 8);
                uint4 g4 = *(const uint4*)(xs + (size_t)c2 * 32 + half * 16);
                uint4 g5 = *(const uint4*)(xs + (size_t)c2 * 32 + half * 16 + 8);
                uint4 g6 = *(const uint4*)(xs + (size_t)c3 * 32 + half * 16);
                uint4 g7 = *(const uint4*)(xs + (size_t)c3 * 32 + half * 16 + 8);
                float2 p;
                p = bfp2f(g0.x); A[0].x += p.x; A[0].y += p.y;
                p = bfp2f(g0.y); A[1].x += p.x; A[1].y += p.y;
                p = bfp2f(g0.z); A[2].x += p.x; A[2].y += p.y;
                p = bfp2f(g0.w); A[3].x += p.x; A[3].y += p.y;
                p = bfp2f(g1.x); A[4].x += p.x; A[4].y += p.y;
                p = bfp2f(g1.y); A[5].x += p.x; A[5].y += p.y;
                p = bfp2f(g1.z); A[6].x += p.x; A[6].y += p.y;
                p = bfp2f(g1.w); A[7].x += p.x; A[7].y += p.y;
                p = bfp2f(g2.x); A[0].x += p.x; A[0].y += p.y;
                p = bfp2f(g2.y); A[1].x += p.x; A[1].y += p.y;
                p = bfp2f(g2.z); A[2].x += p.x; A[2].y += p.y;
                p = bfp2f(g2.w); A[3].x += p.x; A[3].y += p.y;
                p = bfp2f(g3.x); A[4].x += p.x; A[4].y += p.y;
                p = bfp2f(g3.y); A[5].x += p.x; A[5].y += p.y;
                p = bfp2f(g3.z); A[6].x += p.x; A[6].y += p.y;
                p = bfp2f(g3.w); A[7].x += p.x; A[7].y += p.y;
                p = bfp2f(g4.x); A[0].x += p.x; A[0].y += p.y;
                p = bfp2f(g4.y); A[1].x += p.x; A[1].y += p.y;
                p = bfp2f(g4.z); A[2].x += p.x; A[2].y += p.y;
                p = bfp2f(g4.w); A[3].x += p.x; A[3].y += p.y;
                p = bfp2f(g5.x); A[4].x += p.x; A[4].y += p.y;
                p = bfp2f(g5.y); A[5].x += p.x; A[5].y += p.y;
                p = bfp2f(g5.z); A[6].x += p.x; A[6].y += p.y;
                p = bfp2f(g5.w); A[7].x += p.x; A[7].y += p.y;
                p = bfp2f(g6.x); A[0].x += p.x; A[0].y += p.y;
                p = bfp2f(g6.y); A[1].x += p.x; A[1].y += p.y;
                p = bfp2f(g6.z); A[2].x += p.x; A[2].y += p.y;
                p = bfp2f(g6.w); A[3].x += p.x; A[3].y += p.y;
                p = bfp2f(g7.x); A[4].x += p.x; A[4].y += p.y;
                p = bfp2f(g7.y); A[5].x += p.x; A[5].y += p.y;
                p = bfp2f(g7.z); A[6].x += p.x; A[6].y += p.y;
                p = bfp2f(g7.w); A[7].x += p.x; A[7].y += p.y;
            }
            for (; i < end; ++i) {
                int c = col[i];
                uint4 g0 = *(const uint4*)(xs + (size_t)c * 32 + half * 16);
                uint4 g1 = *(const uint4*)(xs + (size_t)c * 32 + half * 16 + 8);
                float2 p;
                p = bfp2f(g0.x); A[0].x += p.x; A[0].y += p.y;
                p = bfp2f(g0.y); A[1].x += p.x; A[1].y += p.y;
                p = bfp2f(g0.z); A[2].x += p.x; A[2].y += p.y;
                p = bfp2f(g0.w); A[3].x += p.x; A[3].y += p.y;
                p = bfp2f(g1.x); A[4].x += p.x; A[4].y += p.y;
                p = bfp2f(g1.y); A[5].x += p.x; A[5].y += p.y;
                p = bfp2f(g1.z); A[6].x += p.x; A[6].y += p.y;
                p = bfp2f(g1.w); A[7].x += p.x; A[7].y += p.y;
            }
            const float dv = dinv[v];
            uint4 o0, o1;
            o0.x = packbf2(dv * A[0].x, dv * A[0].y);
            o0.y = packbf2(dv * A[1].x, dv * A[1].y);
            o0.z = packbf2(dv * A[2].x, dv * A[2].y);
            o0.w = packbf2(dv * A[3].x, dv * A[3].y);
            o1.x = packbf2(dv * A[4].x, dv * A[4].y);
            o1.y = packbf2(dv * A[5].x, dv * A[5].y);
            o1.z = packbf2(dv * A[6].x, dv * A[6].y);
            o1.w = packbf2(dv * A[7].x, dv * A[7].y);
            *(uint4*)(xlds + nloc * 64 + half * 32)      = o0;
            *(uint4*)(xlds + nloc * 64 + half * 32 + 16) = o1;
        } else {
            uint4 z = {0, 0, 0, 0};
            *(uint4*)(xlds + nloc * 64 + half * 32)      = z;
            *(uint4*)(xlds + nloc * 64 + half * 32 + 16) = z;
        }
    }
    __syncthreads();

    // ---- phase 2: MFMA (node1) ----
    const int w = tid >> 6, lane = tid & 63, r = lane & 31, kg = lane >> 5;
    const int nb = blockIdx.x * 128 + w * 32;

    bf16x8 a0[2], a1[2];
#pragma unroll
    for (int t = 0; t < 2; ++t) {
        a0[t] = *(const bf16x8*)&W1T[r * 32 + t * 16 + kg * 8];
        a1[t] = *(const bf16x8*)&W1T[(r + 32) * 32 + t * 16 + kg * 8];
    }

    f32x16 acc0 = {0.f}, acc1 = {0.f};
#pragma unroll
    for (int t = 0; t < 2; ++t) {
        bf16x8 b = *(const bf16x8*)(xlds + (w * 32 + r) * 64 + (t * 16 + kg * 8) * 2);
        acc0 = __builtin_amdgcn_mfma_f32_32x32x16_bf16(a0[t], b, acc0, 0, 0, 0);
        acc1 = __builtin_amdgcn_mfma_f32_32x32x16_bf16(a1[t], b, acc1, 0, 0, 0);
    }

    const int node = nb + r;
    if (node < n) {
        const float dv = dinv[node];
#pragma unroll
        for (int q = 0; q < 4; ++q) {
            const int j0 = 8 * q + 4 * kg;
            float4 bA = *(const float4*)&b1[j0];
            float4 bB = *(const float4*)&b1[j0 + 32];
            short4 s0, s1;
            float t0, t1;
            t0 = acc0[4 * q]     + bA.x; t0 = t0 > 0.f ? t0 : 0.f; s0.x = f2bf(t0 * dv);
            t0 = acc0[4 * q + 1] + bA.y; t0 = t0 > 0.f ? t0 : 0.f; s0.y = f2bf(t0 * dv);
            t0 = acc0[4 * q + 2] + bA.z; t0 = t0 > 0.f ? t0 : 0.f; s0.z = f2bf(t0 * dv);
            t0 = acc0[4 * q + 3] + bA.w; t0 = t0 > 0.f ? t0 : 0.f; s0.w = f2bf(t0 * dv);
            t1 = acc1[4 * q]     + bB.x; t1 = t1 > 0.f ? t1 : 0.f; s1.x = f2bf(t1 * dv);
            t1 = acc1[4 * q + 1] + bB.y; t1 = t1 > 0.f ? t1 : 0.f; s1.y = f2bf(t1 * dv);
            t1 = acc1[4 * q + 2] + bB.z; t1 = t1 > 0.f ? t1 : 0.f; s1.z = f2bf(t1 * dv);
            t1 = acc1[4 * q + 3] + bB.w; t1 = t1 > 0.f ? t1 : 0.f; s1.w = f2bf(t1 * dv);
            *(short4*)&h1s[(size_t)node * 64 + j0]      = s0;
            *(short4*)&h1s[(size_t)node * 64 + j0 + 32] = s1;
        }
    }
}

// ---------------- 64-dim aggregation: 16 lanes/node, uint2 = full 128B row ----------------
__global__ __launch_bounds__(256) void k_agg64(const unsigned short* __restrict__ hsc,
                                               const float* __restrict__ dinv,
                                               const int* __restrict__ rs, const int* __restrict__ col,
                                               unsigned short* __restrict__ out, int n)
{
    const int tid = threadIdx.x;
    const int l   = tid & 15;
    const int v   = blockIdx.x * 16 + (tid >> 4);
    if (v >= n) return;

    uint2 sv = *(const uint2*)(hsc + (size_t)v * 64 + l * 4);
    float2 aL = bfp2f(sv.x), aH = bfp2f(sv.y);
    int i = rs[v];
    const int end = rs[v + 1];
    for (; i + 8 <= end; i += 8) {
        int c0 = col[i],     c1 = col[i + 1], c2 = col[i + 2], c3 = col[i + 3];
        int c4 = col[i + 4], c5 = col[i + 5], c6 = col[i + 6], c7 = col[i + 7];
        uint2 u0 = *(const uint2*)(hsc + (size_t)c0 * 64 + l * 4);
        uint2 u1 = *(const uint2*)(hsc + (size_t)c1 * 64 + l * 4);
        uint2 u2 = *(const uint2*)(hsc + (size_t)c2 * 64 + l * 4);
        uint2 u3 = *(const uint2*)(hsc + (size_t)c3 * 64 + l * 4);
        uint2 u4 = *(const uint2*)(hsc + (size_t)c4 * 64 + l * 4);
        uint2 u5 = *(const uint2*)(hsc + (size_t)c5 * 64 + l * 4);
        uint2 u6 = *(const uint2*)(hsc + (size_t)c6 * 64 + l * 4);
        uint2 u7 = *(const uint2*)(hsc + (size_t)c7 * 64 + l * 4);
        float2 p;
        p = bfp2f(u0.x); aL.x += p.x; aL.y += p.y; p = bfp2f(u0.y); aH.x += p.x; aH.y += p.y;
        p = bfp2f(u1.x); aL.x += p.x; aL.y += p.y; p = bfp2f(u1.y); aH.x += p.x; aH.y += p.y;
        p = bfp2f(u2.x); aL.x += p.x; aL.y += p.y; p = bfp2f(u2.y); aH.x += p.x; aH.y += p.y;
        p = bfp2f(u3.x); aL.x += p.x; aL.y += p.y; p = bfp2f(u3.y); aH.x += p.x; aH.y += p.y;
        p = bfp2f(u4.x); aL.x += p.x; aL.y += p.y; p = bfp2f(u4.y); aH.x += p.x; aH.y += p.y;
        p = bfp2f(u5.x); aL.x += p.x; aL.y += p.y; p = bfp2f(u5.y); aH.x += p.x; aH.y += p.y;
        p = bfp2f(u6.x); aL.x += p.x; aL.y += p.y; p = bfp2f(u6.y); aH.x += p.x; aH.y += p.y;
        p = bfp2f(u7.x); aL.x += p.x; aL.y += p.y; p = bfp2f(u7.y); aH.x += p.x; aH.y += p.y;
    }
    for (; i < end; ++i) {
        uint2 u = *(const uint2*)(hsc + (size_t)col[i] * 64 + l * 4);
        float2 p;
        p = bfp2f(u.x); aL.x += p.x; aL.y += p.y;
        p = bfp2f(u.y); aH.x += p.x; aH.y += p.y;
    }
    const float dv = dinv[v];
    uint2 o;
    o.x = packbf2(dv * aL.x, dv * aL.y);
    o.y = packbf2(dv * aH.x, dv * aH.y);
    *(uint2*)(out + (size_t)v * 64 + l * 4) = o;
}

// ---------------- MFMA edge MLP (node2 folded in; gathers xagg2) ----------------
template <int ABF>
__global__ __launch_bounds__(256) void k_edge_mlp_mfma(
    const unsigned short* __restrict__ zrow, const void* __restrict__ eattr,
    const int* __restrict__ ei,
    const short* __restrict__ Wc1T, const float* __restrict__ bcp,
    const short* __restrict__ Wc2T, const float* __restrict__ bc2,
    float* __restrict__ out, int E)
{
    __shared__ char slab[4 * 8192];   // 32 KB

    const int tid = threadIdx.x;
    const int w = tid >> 6, lane = tid & 63, r = lane & 31, kg = lane >> 5;
    const int q = lane & 3, sr = lane >> 2;

    char* myslab = slab + w * 8192;

    const long eb = (long)blockIdx.x * 128 + w * 32;
    long ecl = eb + r; if (ecl >= E) ecl = E - 1;
    const int ns = ei[ecl];
    const int nd = ei[E + ecl];

    bf16x8 aa;
    if (ABF) {
        aa = *(const bf16x8*)((const unsigned short*)eattr + (size_t)ecl * 16 + kg * 8);
    } else {
        const float* arow = (const float*)eattr + (size_t)ecl * 16;
        float4 alo = *(const float4*)&arow[kg * 8];
        float4 ahi = *(const float4*)&arow[kg * 8 + 4];
        aa[0] = f2bf(alo.x); aa[1] = f2bf(alo.y); aa[2] = f2bf(alo.z); aa[3] = f2bf(alo.w);
        aa[4] = f2bf(ahi.x); aa[5] = f2bf(ahi.y); aa[6] = f2bf(ahi.z); aa[7] = f2bf(ahi.w);
    }

    // coop gathers: 4-lane groups fetch contiguous 64B per row
    {
        int n0 = __shfl(ns, sr);
        int n1 = __shfl(ns, 16 + sr);
        int m0 = __shfl(nd, sr);
        int m1 = __shfl(nd, 16 + sr);
        int4 s0 = *(const int4*)&zrow[(size_t)n0 * 64 + q * 8];
        int4 s1 = *(const int4*)&zrow[(size_t)n0 * 64 + 32 + q * 8];
        int4 s2 = *(const int4*)&zrow[(size_t)n1 * 64 + q * 8];
        int4 s3 = *(const int4*)&zrow[(size_t)n1 * 64 + 32 + q * 8];
        int4 d0 = *(const int4*)&zrow[(size_t)m0 * 64 + q * 8];
        int4 d1 = *(const int4*)&zrow[(size_t)m0 * 64 + 32 + q * 8];
        int4 d2 = *(const int4*)&zrow[(size_t)m1 * 64 + q * 8];
        int4 d3 = *(const int4*)&zrow[(size_t)m1 * 64 + 32 + q * 8];
        const int x0 = (sr ^ q) * 16, x1 = (16 + (sr ^ q)) * 16;
        *(int4*)(myslab + q * 512 + x0)              = s0;
        *(int4*)(myslab + (4 + q) * 512 + x0)        = s1;
        *(int4*)(myslab + q * 512 + x1)              = s2;
        *(int4*)(myslab + (4 + q) * 512 + x1)        = s3;
        *(int4*)(myslab + 4096 + q * 512 + x0)       = d0;
        *(int4*)(myslab + 4096 + (4 + q) * 512 + x0) = d1;
        *(int4*)(myslab + 4096 + q * 512 + x1)       = d2;
        *(int4*)(myslab + 4096 + (4 + q) * 512 + x1) = d3;
    }

    f32x16 acc0, acc1;
    const float bias0 = bcp[r], bias1 = bcp[r + 32];
#pragma unroll
    for (int i = 0; i < 16; ++i) { acc0[i] = bias0; acc1[i] = bias1; }

#pragma unroll
    for (int t = 0; t < 4; ++t) {
        const int c = 2 * t + kg;
        bf16x8 a  = *(const bf16x8*)(myslab + c * 512 + ((r ^ (c & 3)) * 16));
        bf16x8 w0 = *(const bf16x8*)&Wc1T[r * 144 + t * 16 + kg * 8];
        bf16x8 w1 = *(const bf16x8*)&Wc1T[(r + 32) * 144 + t * 16 + kg * 8];
        acc0 = __builtin_amdgcn_mfma_f32_32x32x16_bf16(a, w0, acc0, 0, 0, 0);
        acc1 = __builtin_amdgcn_mfma_f32_32x32x16_bf16(a, w1, acc1, 0, 0, 0);
    }
#pragma unroll
    for (int t = 0; t < 4; ++t) {
        const int c = 2 * t + kg;
        bf16x8 a  = *(const bf16x8*)(myslab + 4096 + c * 512 + ((r ^ (c & 3)) * 16));
        bf16x8 w0 = *(const bf16x8*)&Wc1T[r * 144 + (4 + t) * 16 + kg * 8];
        bf16x8 w1 = *(const bf16x8*)&Wc1T[(r + 32) * 144 + (4 + t) * 16 + kg * 8];
        acc0 = __builtin_amdgcn_mfma_f32_32x32x16_bf16(a, w0, acc0, 0, 0, 0);
        acc1 = __builtin_amdgcn_mfma_f32_32x32x16_bf16(a, w1, acc1, 0, 0, 0);
    }
    {
        bf16x8 w0 = *(const bf16x8*)&Wc1T[r * 144 + 128 + kg * 8];
        bf16x8 w1 = *(const bf16x8*)&Wc1T[(r + 32) * 144 + 128 + kg * 8];
        acc0 = __builtin_amdgcn_mfma_f32_32x32x16_bf16(aa, w0, acc0, 0, 0, 0);
        acc1 = __builtin_amdgcn_mfma_f32_32x32x16_bf16(aa, w1, acc1, 0, 0, 0);
    }

    // epilogue 1: relu -> packed u32 (col r, col r+32) -> swizzled hid (src half)
#pragma unroll
    for (int reg = 0; reg < 16; ++reg) {
        const int row = (reg & 3) + 8 * (reg >> 2) + 4 * kg;
        float v0 = acc0[reg]; v0 = v0 > 0.f ? v0 : 0.f;
        float v1 = acc1[reg]; v1 = v1 > 0.f ? v1 : 0.f;
        *(unsigned*)(myslab + row * 128 + ((4 * r) ^ ((row & 7) << 4))) = packbf2(v0, v1);
    }

    // layer 2 (k-space permuted to match Wc2T)
    const float bias2 = (r < 5) ? bc2[r] : 0.f;
    f32x16 acc2;
#pragma unroll
    for (int i = 0; i < 16; ++i) acc2[i] = bias2;
#pragma unroll
    for (int t2 = 0; t2 < 4; ++t2) {
        const int m = t2 * 2 + kg;
        bf16x8 a  = *(const bf16x8*)(myslab + r * 128 + ((16 * m) ^ ((r & 7) << 4)));
        bf16x8 bw = *(const bf16x8*)&Wc2T[r * 64 + t2 * 16 + kg * 8];
        acc2 = __builtin_amdgcn_mfma_f32_32x32x16_bf16(a, bw, acc2, 0, 0, 0);
    }

    // stores (edge order: contiguous 640B per wave)
#pragma unroll
    for (int reg = 0; reg < 16; ++reg) {
        const int row = (reg & 3) + 8 * (reg >> 2) + 4 * kg;
        const long eo = eb + row;
        if (r < 5 && eo < E) out[(size_t)eo * 5 + r] = acc2[reg];
    }
}

extern "C" void kernel_launch(void* const* d_in, const int* in_sizes, int n_in,
                              void* d_out, int out_size, void* d_ws, size_t ws_size,
                              hipStream_t stream)
{
    const float* x     = (const float*)d_in[0];
    const int*   ei    = (const int*)d_in[1];
    const float* eattr = (const float*)d_in[2];
    const float* W1    = (const float*)d_in[3];
    const float* b1    = (const float*)d_in[4];
    const float* W2    = (const float*)d_in[5];
    const float* b2    = (const float*)d_in[6];
    const float* Wc1   = (const float*)d_in[7];
    const float* bc1   = (const float*)d_in[8];
    const float* Wc2   = (const float*)d_in[9];
    const float* bc2   = (const float*)d_in[10];
    float* outp = (float*)d_out;

    const int N = in_sizes[0] / 32;
    const int E = in_sizes[1] / 2;
    const int nbk = (N + 255) >> 8;

    // ---- carve workspace ----
    size_t off = 0;
    char* base = (char*)d_ws;
    auto carve = [&](size_t bytes) -> void* {
        void* p = base + off;
        off += (bytes + 255) & ~(size_t)255;
        return p;
    };
    int*   bcnt   = (int*)carve(1024 * 4);           // bcnt + bcur adjacent
    int*   bcur   = bcnt + 512;
    int*   bstart = (int*)carve(520 * 4);
    float* dinv   = (float*)carve((size_t)N * 4);
    int*   rs     = (int*)carve((size_t)(N + 1) * 4);
    int*   col    = (int*)carve((size_t)E * 4);
    int2*  ebs    = (int2*)carve((size_t)E * 8);
    unsigned short* xs    = (unsigned short*)carve((size_t)N * 32 * 2);
    unsigned short* h1s   = (unsigned short*)carve((size_t)N * 64 * 2);
    unsigned short* xagg2 = (unsigned short*)carve((size_t)N * 64 * 2);
    short* Wc1T   = (short*)carve(9216 * 2);
    short* Wc2T   = (short*)carve(2048 * 2);
    short* W1T    = (short*)carve(2048 * 2);
    float* bcp    = (float*)carve(64 * 4);
    unsigned short* eabf = (unsigned short*)carve((size_t)E * 16 * 2);   // optional
    const bool use_abf = (off <= ws_size);
    (void)n_in; (void)out_size;

    const int NAN1 = (N + 127) / 128;    // aggnode1: 128 nodes/block
    const int NA   = (N + 15) / 16;      // agg64: 16 nodes/block
    const int NT   = (E + 127) / 128;    // edge-MLP: 128 edges/block
    const int NSC  = (E + 4095) / 4096;  // binscatter chunks

    hipMemsetAsync(bcnt, 0, 1024 * 4, stream);

    // fused prep + histogram + attr-convert
    k_prep_hist_ea<<<68 + 1024, 256, 0, stream>>>(Wc1, Wc2, W2, W1, bc1, b2,
                                                  Wc1T, Wc2T, W1T, bcp,
                                                  ei, bcnt, eattr, eabf, E, use_abf ? 1 : 0);
    k_bscan<<<1, 512, 0, stream>>>(bcnt, nbk, bstart);
    k_binscatter<<<NSC, 256, 0, stream>>>(ei, bstart, bcur, ebs, E);
    k_build<<<nbk, 256, 0, stream>>>(ebs, bstart, rs, col, dinv, x, xs, N, E);

    // GCN layers (agg_x + node1 fused; node2 folded into MLP)
    k_aggnode1<<<NAN1, 256, 0, stream>>>(xs, dinv, rs, col, W1T, b1, h1s, N);
    k_agg64<<<NA, 256, 0, stream>>>(h1s, dinv, rs, col, xagg2, N);

    // edge MLP
    if (use_abf)
        k_edge_mlp_mfma<1><<<NT, 256, 0, stream>>>(xagg2, eabf, ei, Wc1T, bcp, Wc2T, bc2, outp, E);
    else
        k_edge_mlp_mfma<0><<<NT, 256, 0, stream>>>(xagg2, eattr, ei, Wc1T, bcp, Wc2T, bc2, outp, E);
}